// Round 2
// baseline (591.663 us; speedup 1.0000x reference)
//
#include <hip/hip_runtime.h>
#include <math.h>

typedef float f32x4 __attribute__((ext_vector_type(4)));
typedef __bf16 bf16x8 __attribute__((ext_vector_type(8)));
typedef unsigned short u16x8 __attribute__((ext_vector_type(8)));
typedef unsigned short u16x4 __attribute__((ext_vector_type(4)));

#define LN2F_ 0.69314718055994530942f

__device__ inline unsigned short f2bf(float f) {
    unsigned u = __builtin_bit_cast(unsigned, f);
    u += 0x7fffu + ((u >> 16) & 1u);
    return (unsigned short)(u >> 16);
}

// ---------------------------------------------------------------------------
// Swizzled LDS tile: tile = R rows x 32 k (bf16), stored as 16B blocks.
//   addr(row, c) = (row>>4)*512 + ((c<<4) + ((row&15) ^ (c<<1))) * 8   [shorts]
// Verified by enumeration: every 8-lane phase of the staging writes AND the
// fragment reads covers all 32 banks exactly once -> conflict-free, and
// fragment reads are lane-contiguous 1 KiB per wave.
// ---------------------------------------------------------------------------
__device__ inline void stage_st(unsigned short* Ls, int row, int c, u16x8 v) {
    *(u16x8*)(Ls + (row >> 4) * 512 + (((c) << 4) + ((row & 15) ^ ((c) << 1))) * 8) = v;
}
__device__ inline bf16x8 frag_ld(const unsigned short* Ls, int s, int ml, int q) {
    return __builtin_bit_cast(bf16x8,
        *(const u16x8*)(Ls + s * 512 + (((q) << 4) + (ml ^ ((q) << 1))) * 8));
}

// ---------------------------------------------------------------------------
// fp32 -> bf16 bulk convert (used only for V, tiny)
// ---------------------------------------------------------------------------
__global__ __launch_bounds__(256) void k_cvt(const float* __restrict__ in,
                                             unsigned short* __restrict__ out, int n4) {
    int i = blockIdx.x * 256 + threadIdx.x;
    if (i >= n4) return;
    float4 v = ((const float4*)in)[i];
    u16x4 o = { f2bf(v.x), f2bf(v.y), f2bf(v.z), f2bf(v.w) };
    *(u16x4*)(out + (size_t)i * 4) = o;
}

// am[h][p][j] = bf16(alpha[h][(j - p) & 1023])
__global__ __launch_bounds__(256) void k_build_am(const float* __restrict__ alpha,
                                                  unsigned short* __restrict__ am) {
    int t = blockIdx.x * 256 + threadIdx.x;          // 0 .. 1048575
    int j8 = (t & 127) << 3;
    int p  = (t >> 7) & 1023;
    int h  = t >> 17;
    const float* ar = alpha + (h << 10);
    u16x8 o;
#pragma unroll
    for (int q = 0; q < 8; ++q) o[q] = f2bf(ar[(j8 + q - p) & 1023]);
    *(u16x8*)(am + ((size_t)t << 3)) = o;
}

// WT[e'][e] = bf16(W[e][e'])
__global__ __launch_bounds__(256) void k_build_wt(const float* __restrict__ W,
                                                  unsigned short* __restrict__ WT) {
    int t = blockIdx.x * 256 + threadIdx.x;          // 0 .. 262143
    int e1 = t >> 9, e = t & 511;
    WT[t] = f2bf(W[e * 512 + e1]);
}

// ---------------------------------------------------------------------------
// K1: wsT[n][e][p] = sum_d x[(n,p)][d] * Vb[e][d]   (x fp32, converted in-kernel)
//   BM=64, BN=512 (full E -> X read exactly once), BK=32.
//   256 threads = 4 waves; each wave 64m x 128e, acc[4][8], 32 MFMA/K-step.
//   Vb (0.5 MB) is L2-resident; per-block re-reads are free.
//   ~210 VGPR incl AGPR -> 2 blocks/CU resident (cross-block barrier overlap).
// ---------------------------------------------------------------------------
__global__ __launch_bounds__(256) void k_gemm1(const float* __restrict__ X,
                                               const unsigned short* __restrict__ B,
                                               unsigned short* __restrict__ wsT) {
    __shared__ __align__(16) unsigned short As[64 * 32];
    __shared__ __align__(16) unsigned short Bs[512 * 32];
    const int tid = threadIdx.x;
    const int m0 = blockIdx.x * 64;
    const int w = tid >> 6, lane = tid & 63, ml = lane & 15, quad = lane >> 4;
    const int arow = tid >> 2, ac = tid & 3;         // 64 rows x 4 chunks
    const float* apb = X + (size_t)(m0 + arow) * 512 + ac * 8;
    const unsigned short* bp0 = B + (size_t)tid * 512;
    const unsigned short* bp1 = B + (size_t)(tid + 256) * 512;
    f32x4 acc[4][8] = {};
    for (int k0 = 0; k0 < 512; k0 += 32) {
        float4 a0 = ((const float4*)(apb + k0))[0];
        float4 a1 = ((const float4*)(apb + k0))[1];
        u16x8 rb0[4], rb1[4];
#pragma unroll
        for (int c = 0; c < 4; ++c) {
            rb0[c] = *(const u16x8*)(bp0 + k0 + c * 8);
            rb1[c] = *(const u16x8*)(bp1 + k0 + c * 8);
        }
        __syncthreads();
        u16x8 pa = { f2bf(a0.x), f2bf(a0.y), f2bf(a0.z), f2bf(a0.w),
                     f2bf(a1.x), f2bf(a1.y), f2bf(a1.z), f2bf(a1.w) };
        stage_st(As, arow, ac, pa);
#pragma unroll
        for (int c = 0; c < 4; ++c) {
            stage_st(Bs, tid, c, rb0[c]);
            stage_st(Bs, tid + 256, c, rb1[c]);
        }
        __syncthreads();
        bf16x8 af[4], bfr[8];
#pragma unroll
        for (int i = 0; i < 4; ++i) af[i] = frag_ld(As, i, ml, quad);
#pragma unroll
        for (int j = 0; j < 8; ++j) bfr[j] = frag_ld(Bs, w * 8 + j, ml, quad);
#pragma unroll
        for (int i = 0; i < 4; ++i)
#pragma unroll
            for (int j = 0; j < 8; ++j)
                acc[i][j] = __builtin_amdgcn_mfma_f32_16x16x32_bf16(af[i], bfr[j], acc[i][j], 0, 0, 0);
    }
    const int n = m0 >> 10;
    const int pblk = m0 & 1023;
#pragma unroll
    for (int i = 0; i < 4; ++i) {
        int p = pblk + i * 16 + quad * 4;
#pragma unroll
        for (int j = 0; j < 8; ++j) {
            int e = w * 128 + j * 16 + ml;
            u16x4 o = { f2bf(acc[i][j][0]), f2bf(acc[i][j][1]),
                        f2bf(acc[i][j][2]), f2bf(acc[i][j][3]) };
            *(u16x4*)(wsT + ((size_t)n * 512 + e) * 1024 + p) = o;
        }
    }
}

// ---------------------------------------------------------------------------
// K2: y[n][p][h*64+r] = sum_j am[h][p][j] * wsT[n][h*64+r][j]
//   n-batched: each block does NB=4 n-values sharing one am tile.
//   512 threads = 8 waves = (4 n) x (2 p-halves); each wave 64r x 64p.
// ---------------------------------------------------------------------------
__global__ __launch_bounds__(512) void k_gemm2(const unsigned short* __restrict__ wsT,
                                               const unsigned short* __restrict__ am,
                                               unsigned short* __restrict__ y) {
    __shared__ __align__(16) unsigned short As[256 * 32];   // rows: wn*64 + r
    __shared__ __align__(16) unsigned short Bs[128 * 32];   // rows: p - p0
    const int tid = threadIdx.x;
    const int p0 = blockIdx.x * 128;
    const int h  = blockIdx.y;
    const int n0 = blockIdx.z * 4;
    const int w = tid >> 6, lane = tid & 63, ml = lane & 15, quad = lane >> 4;
    const int wn = w >> 1, wp = w & 1;
    const int arow = tid >> 1, ahalf = tid & 1;      // 256 A rows, 2 thr/row, 32B
    const int brow = tid >> 2, bc = tid & 3;         // 128 B rows, 4 thr/row, 16B
    const unsigned short* Ap = wsT + (size_t)(n0 + (arow >> 6)) * 524288
                                   + (size_t)(h * 64 + (arow & 63)) * 1024 + ahalf * 16;
    const unsigned short* Bp = am + ((size_t)h * 1024 + p0 + brow) * 1024 + bc * 8;
    f32x4 acc[4][4] = {};
    for (int j0 = 0; j0 < 1024; j0 += 32) {
        u16x8 ra0 = *(const u16x8*)(Ap + j0);
        u16x8 ra1 = *(const u16x8*)(Ap + j0 + 8);
        u16x8 rb  = *(const u16x8*)(Bp + j0);
        __syncthreads();
        stage_st(As, arow, ahalf * 2 + 0, ra0);
        stage_st(As, arow, ahalf * 2 + 1, ra1);
        stage_st(Bs, brow, bc, rb);
        __syncthreads();
        bf16x8 af[4], bfr[4];
#pragma unroll
        for (int mt = 0; mt < 4; ++mt)
            af[mt] = frag_ld(As, wn * 4 + mt, ml, quad);
#pragma unroll
        for (int nt = 0; nt < 4; ++nt)
            bfr[nt] = frag_ld(Bs, wp * 4 + nt, ml, quad);
#pragma unroll
        for (int mt = 0; mt < 4; ++mt)
#pragma unroll
            for (int nt = 0; nt < 4; ++nt)
                acc[mt][nt] = __builtin_amdgcn_mfma_f32_16x16x32_bf16(af[mt], bfr[nt], acc[mt][nt], 0, 0, 0);
    }
    const int n = n0 + wn;
#pragma unroll
    for (int mt = 0; mt < 4; ++mt) {
        int r0 = mt * 16 + quad * 4;
#pragma unroll
        for (int nt = 0; nt < 4; ++nt) {
            int p = p0 + wp * 64 + nt * 16 + ml;
            u16x4 o = { f2bf(acc[mt][nt][0]), f2bf(acc[mt][nt][1]),
                        f2bf(acc[mt][nt][2]), f2bf(acc[mt][nt][3]) };
            *(u16x4*)(y + ((size_t)n * 1024 + p) * 512 + h * 64 + r0) = o;
        }
    }
}

// ---------------------------------------------------------------------------
// K3: out[m][e'] = log_cosh( sum_e y[m][e] * WT[e'][e] + b[e'] )  (fp32 out)
//   BM=64, BN=512 (full E -> y read exactly once), same wave layout as K1.
//   Fast epilogue: __expf/__logf (single-instruction transcendentals).
// ---------------------------------------------------------------------------
__global__ __launch_bounds__(256) void k_gemm3(const unsigned short* __restrict__ A,
                                               const unsigned short* __restrict__ B,
                                               const float* __restrict__ bias,
                                               float* __restrict__ out) {
    __shared__ __align__(16) unsigned short As[64 * 32];
    __shared__ __align__(16) unsigned short Bs[512 * 32];
    const int tid = threadIdx.x;
    const int m0 = blockIdx.x * 64;
    const int w = tid >> 6, lane = tid & 63, ml = lane & 15, quad = lane >> 4;
    const int arow = tid >> 2, ac = tid & 3;
    const unsigned short* apb = A + (size_t)(m0 + arow) * 512 + ac * 8;
    const unsigned short* bp0 = B + (size_t)tid * 512;
    const unsigned short* bp1 = B + (size_t)(tid + 256) * 512;
    f32x4 acc[4][8] = {};
    for (int k0 = 0; k0 < 512; k0 += 32) {
        u16x8 ra = *(const u16x8*)(apb + k0);
        u16x8 rb0[4], rb1[4];
#pragma unroll
        for (int c = 0; c < 4; ++c) {
            rb0[c] = *(const u16x8*)(bp0 + k0 + c * 8);
            rb1[c] = *(const u16x8*)(bp1 + k0 + c * 8);
        }
        __syncthreads();
        stage_st(As, arow, ac, ra);
#pragma unroll
        for (int c = 0; c < 4; ++c) {
            stage_st(Bs, tid, c, rb0[c]);
            stage_st(Bs, tid + 256, c, rb1[c]);
        }
        __syncthreads();
        bf16x8 af[4], bfr[8];
#pragma unroll
        for (int i = 0; i < 4; ++i) af[i] = frag_ld(As, i, ml, quad);
#pragma unroll
        for (int j = 0; j < 8; ++j) bfr[j] = frag_ld(Bs, w * 8 + j, ml, quad);
#pragma unroll
        for (int i = 0; i < 4; ++i)
#pragma unroll
            for (int j = 0; j < 8; ++j)
                acc[i][j] = __builtin_amdgcn_mfma_f32_16x16x32_bf16(af[i], bfr[j], acc[i][j], 0, 0, 0);
    }
#pragma unroll
    for (int j = 0; j < 8; ++j) {
        int e = w * 128 + j * 16 + ml;
        float bv = bias[e];
#pragma unroll
        for (int i = 0; i < 4; ++i) {
            int mg = m0 + i * 16 + quad * 4;
#pragma unroll
            for (int r = 0; r < 4; ++r) {
                float v  = acc[i][j][r] + bv;
                float ax = fabsf(v);
                float t  = __expf(-2.0f * ax);
                out[(size_t)(mg + r) * 512 + e] = ax + __logf(1.0f + t) - LN2F_;
            }
        }
    }
}

// ---------------------------------------------------------------------------
// Buffers:
//   d_out: [am 16 MB | Vb 0.5 MB]  (consumed before K3 overwrites d_out)
//   d_ws : [wsT 67 MB (reused for WT after K2) | y 67 MB]
// Order: cvt(V), build_am -> K1 -> K2 -> build_wt -> K3
// ---------------------------------------------------------------------------
extern "C" void kernel_launch(void* const* d_in, const int* in_sizes, int n_in,
                              void* d_out, int out_size, void* d_ws, size_t ws_size,
                              hipStream_t stream) {
    const float* x     = (const float*)d_in[0];
    const float* alpha = (const float*)d_in[1];
    const float* V     = (const float*)d_in[2];
    const float* W     = (const float*)d_in[3];
    const float* b     = (const float*)d_in[4];

    unsigned short* am  = (unsigned short*)d_out;
    unsigned short* Vb  = am + 8388608;
    unsigned short* wsT = (unsigned short*)d_ws;
    unsigned short* y   = wsT + 33554432;
    unsigned short* WT  = wsT;
    float* out = (float*)d_out;

    k_cvt<<<256, 256, 0, stream>>>(V, Vb, 65536);
    k_build_am<<<4096, 256, 0, stream>>>(alpha, am);

    k_gemm1<<<dim3(1024), 256, 0, stream>>>(x, Vb, wsT);
    k_gemm2<<<dim3(8, 8, 16), 512, 0, stream>>>(wsT, am, y);
    k_build_wt<<<1024, 256, 0, stream>>>(W, WT);
    k_gemm3<<<dim3(1024), 256, 0, stream>>>(y, WT, b, out);
}

// Round 3
// 453.580 us; speedup vs baseline: 1.3044x; 1.3044x over previous
//
#include <hip/hip_runtime.h>
#include <math.h>

typedef float f32x4 __attribute__((ext_vector_type(4)));
typedef __bf16 bf16x8 __attribute__((ext_vector_type(8)));
typedef unsigned short u16x8 __attribute__((ext_vector_type(8)));
typedef unsigned short u16x4 __attribute__((ext_vector_type(4)));

#define LN2F_ 0.69314718055994530942f

__device__ inline unsigned short f2bf(float f) {
    unsigned u = __builtin_bit_cast(unsigned, f);
    u += 0x7fffu + ((u >> 16) & 1u);
    return (unsigned short)(u >> 16);
}

// ---------------------------------------------------------------------------
// Swizzled LDS tile: tile = R rows x 32 k (bf16), stored as 16B blocks.
//   addr(row, c) = (row>>4)*512 + ((c<<4) + ((row&15) ^ (c<<1))) * 8   [shorts]
// Verified by enumeration: every 8-lane phase of the staging writes AND the
// fragment reads covers all 32 banks exactly once -> conflict-free, and
// fragment reads are lane-contiguous 1 KiB per wave.
// ---------------------------------------------------------------------------
__device__ inline void stage_st(unsigned short* Ls, int row, int c, u16x8 v) {
    *(u16x8*)(Ls + (row >> 4) * 512 + (((c) << 4) + ((row & 15) ^ ((c) << 1))) * 8) = v;
}
__device__ inline bf16x8 frag_ld(const unsigned short* Ls, int s, int ml, int q) {
    return __builtin_bit_cast(bf16x8,
        *(const u16x8*)(Ls + s * 512 + (((q) << 4) + (ml ^ ((q) << 1))) * 8));
}

// ---------------------------------------------------------------------------
// fp32 -> bf16 bulk convert (used only for V, tiny)
// ---------------------------------------------------------------------------
__global__ __launch_bounds__(256) void k_cvt(const float* __restrict__ in,
                                             unsigned short* __restrict__ out, int n4) {
    int i = blockIdx.x * 256 + threadIdx.x;
    if (i >= n4) return;
    float4 v = ((const float4*)in)[i];
    u16x4 o = { f2bf(v.x), f2bf(v.y), f2bf(v.z), f2bf(v.w) };
    *(u16x4*)(out + (size_t)i * 4) = o;
}

// am[h][p][j] = bf16(alpha[h][(j - p) & 1023])
__global__ __launch_bounds__(256) void k_build_am(const float* __restrict__ alpha,
                                                  unsigned short* __restrict__ am) {
    int t = blockIdx.x * 256 + threadIdx.x;          // 0 .. 1048575
    int j8 = (t & 127) << 3;
    int p  = (t >> 7) & 1023;
    int h  = t >> 17;
    const float* ar = alpha + (h << 10);
    u16x8 o;
#pragma unroll
    for (int q = 0; q < 8; ++q) o[q] = f2bf(ar[(j8 + q - p) & 1023]);
    *(u16x8*)(am + ((size_t)t << 3)) = o;
}

// WT[e'][e] = bf16(W[e][e'])
__global__ __launch_bounds__(256) void k_build_wt(const float* __restrict__ W,
                                                  unsigned short* __restrict__ WT) {
    int t = blockIdx.x * 256 + threadIdx.x;          // 0 .. 262143
    int e1 = t >> 9, e = t & 511;
    WT[t] = f2bf(W[e * 512 + e1]);
}

// ---------------------------------------------------------------------------
// K1: wsT[n][e][p] = sum_d x[(n,p)][d] * Vb[e][d]   (x fp32, converted in-kernel)
//   BM=128, BN=128, BK=32; 4 waves x (64x64).
//   XCD-aware remap (dispatch id -> XCD is round-robin, id%8):
//     xcd = flat&7, slot = flat>>3 (0..255);
//     mpanel = xcd*64 + slot/4  (bijective over [0,512)), eblk = slot&3.
//   -> the 4 e-blocks sharing one 256 KB X panel are co-XCD and consecutive,
//      so X is fetched ~once into that XCD's L2 instead of 4x across XCDs.
// ---------------------------------------------------------------------------
__global__ __launch_bounds__(256) void k_gemm1(const float* __restrict__ X,
                                               const unsigned short* __restrict__ B,
                                               unsigned short* __restrict__ wsT) {
    __shared__ __align__(16) unsigned short As[128 * 32];
    __shared__ __align__(16) unsigned short Bs[128 * 32];
    const int tid = threadIdx.x;
    const int flat = blockIdx.x;
    const int xcd = flat & 7, slot = flat >> 3;
    const int m0 = (xcd * 64 + (slot >> 2)) * 128;
    const int e0 = (slot & 3) * 128;
    const int w = tid >> 6, lane = tid & 63, ml = lane & 15, quad = lane >> 4;
    const int wr = w >> 1, wc = w & 1;
    const int srow = tid >> 1, shalf = tid & 1;      // 128 rows, 2 threads/row
    f32x4 acc[4][4] = {};
    for (int k0 = 0; k0 < 512; k0 += 32) {
        const float* ap = X + (size_t)(m0 + srow) * 512 + k0 + shalf * 16;
        float4 a0 = ((const float4*)ap)[0];
        float4 a1 = ((const float4*)ap)[1];
        float4 a2 = ((const float4*)ap)[2];
        float4 a3 = ((const float4*)ap)[3];
        const unsigned short* bp = B + (size_t)(e0 + srow) * 512 + k0 + shalf * 16;
        u16x8 rb0 = *(const u16x8*)bp;
        u16x8 rb1 = *(const u16x8*)(bp + 8);
        __syncthreads();
        u16x8 pa0 = { f2bf(a0.x), f2bf(a0.y), f2bf(a0.z), f2bf(a0.w),
                      f2bf(a1.x), f2bf(a1.y), f2bf(a1.z), f2bf(a1.w) };
        u16x8 pa1 = { f2bf(a2.x), f2bf(a2.y), f2bf(a2.z), f2bf(a2.w),
                      f2bf(a3.x), f2bf(a3.y), f2bf(a3.z), f2bf(a3.w) };
        stage_st(As, srow, shalf * 2 + 0, pa0);
        stage_st(As, srow, shalf * 2 + 1, pa1);
        stage_st(Bs, srow, shalf * 2 + 0, rb0);
        stage_st(Bs, srow, shalf * 2 + 1, rb1);
        __syncthreads();
        bf16x8 af[4], bfr[4];
#pragma unroll
        for (int i = 0; i < 4; ++i) {
            af[i]  = frag_ld(As, wr * 4 + i, ml, quad);
            bfr[i] = frag_ld(Bs, wc * 4 + i, ml, quad);
        }
#pragma unroll
        for (int i = 0; i < 4; ++i)
#pragma unroll
            for (int j = 0; j < 4; ++j)
                acc[i][j] = __builtin_amdgcn_mfma_f32_16x16x32_bf16(af[i], bfr[j], acc[i][j], 0, 0, 0);
    }
    const int n = m0 >> 10;
    const int pblk = m0 & 1023;
#pragma unroll
    for (int i = 0; i < 4; ++i) {
        int p = pblk + wr * 64 + i * 16 + quad * 4;
#pragma unroll
        for (int j = 0; j < 4; ++j) {
            int e = e0 + wc * 64 + j * 16 + ml;
            u16x4 o = { f2bf(acc[i][j][0]), f2bf(acc[i][j][1]),
                        f2bf(acc[i][j][2]), f2bf(acc[i][j][3]) };
            *(u16x4*)(wsT + ((size_t)n * 512 + e) * 1024 + p) = o;
        }
    }
}

// ---------------------------------------------------------------------------
// K2: y[n][p][h*64+r] = sum_j am[h][p][j] * wsT[n][h*64+r][j]
//   n-batched: each block does NB=4 n-values sharing one am tile.
//   512 threads = 8 waves = (4 n) x (2 p-halves); each wave 64r x 64p.
//   XCD-aware remap: panel = (h, n-group); the 8 p-blocks sharing one 512 KB
//   wsT A-panel are made co-XCD (A fetched once per panel instead of 8x):
//     xcd = flat&7, slot = flat>>3 (0..127);
//     panel = xcd*16 + slot/8  (bijective over [0,128)), px = slot&7.
// ---------------------------------------------------------------------------
__global__ __launch_bounds__(512) void k_gemm2(const unsigned short* __restrict__ wsT,
                                               const unsigned short* __restrict__ am,
                                               unsigned short* __restrict__ y) {
    __shared__ __align__(16) unsigned short As[256 * 32];   // rows: wn*64 + r
    __shared__ __align__(16) unsigned short Bs[128 * 32];   // rows: p - p0
    const int tid = threadIdx.x;
    const int flat = blockIdx.x;
    const int xcd = flat & 7, slot = flat >> 3;
    const int panel = xcd * 16 + (slot >> 3);
    const int p0 = (slot & 7) * 128;
    const int h  = panel & 7;
    const int n0 = (panel >> 3) * 4;
    const int w = tid >> 6, lane = tid & 63, ml = lane & 15, quad = lane >> 4;
    const int wn = w >> 1, wp = w & 1;
    const int arow = tid >> 1, ahalf = tid & 1;      // 256 A rows, 2 thr/row, 32B
    const int brow = tid >> 2, bc = tid & 3;         // 128 B rows, 4 thr/row, 16B
    const unsigned short* Ap = wsT + (size_t)(n0 + (arow >> 6)) * 524288
                                   + (size_t)(h * 64 + (arow & 63)) * 1024 + ahalf * 16;
    const unsigned short* Bp = am + ((size_t)h * 1024 + p0 + brow) * 1024 + bc * 8;
    f32x4 acc[4][4] = {};
    for (int j0 = 0; j0 < 1024; j0 += 32) {
        u16x8 ra0 = *(const u16x8*)(Ap + j0);
        u16x8 ra1 = *(const u16x8*)(Ap + j0 + 8);
        u16x8 rb  = *(const u16x8*)(Bp + j0);
        __syncthreads();
        stage_st(As, arow, ahalf * 2 + 0, ra0);
        stage_st(As, arow, ahalf * 2 + 1, ra1);
        stage_st(Bs, brow, bc, rb);
        __syncthreads();
        bf16x8 af[4], bfr[4];
#pragma unroll
        for (int mt = 0; mt < 4; ++mt)
            af[mt] = frag_ld(As, wn * 4 + mt, ml, quad);
#pragma unroll
        for (int nt = 0; nt < 4; ++nt)
            bfr[nt] = frag_ld(Bs, wp * 4 + nt, ml, quad);
#pragma unroll
        for (int mt = 0; mt < 4; ++mt)
#pragma unroll
            for (int nt = 0; nt < 4; ++nt)
                acc[mt][nt] = __builtin_amdgcn_mfma_f32_16x16x32_bf16(af[mt], bfr[nt], acc[mt][nt], 0, 0, 0);
    }
    const int n = n0 + wn;
#pragma unroll
    for (int mt = 0; mt < 4; ++mt) {
        int r0 = mt * 16 + quad * 4;
#pragma unroll
        for (int nt = 0; nt < 4; ++nt) {
            int p = p0 + wp * 64 + nt * 16 + ml;
            u16x4 o = { f2bf(acc[mt][nt][0]), f2bf(acc[mt][nt][1]),
                        f2bf(acc[mt][nt][2]), f2bf(acc[mt][nt][3]) };
            *(u16x4*)(y + ((size_t)n * 1024 + p) * 512 + h * 64 + r0) = o;
        }
    }
}

// ---------------------------------------------------------------------------
// K3: out[m][e'] = log_cosh( sum_e y[m][e] * WT[e'][e] + b[e'] )  (fp32 out)
//   BM=128, BN=128 structure (reverted from BN=512 — that collapsed occupancy).
//   Same XCD-aware remap as K1: 4 e-blocks per 128 KB y panel co-XCD.
//   Fast epilogue: __expf/__logf (single-instruction transcendentals).
// ---------------------------------------------------------------------------
__global__ __launch_bounds__(256) void k_gemm3(const unsigned short* __restrict__ A,
                                               const unsigned short* __restrict__ B,
                                               const float* __restrict__ bias,
                                               float* __restrict__ out) {
    __shared__ __align__(16) unsigned short As[128 * 32];
    __shared__ __align__(16) unsigned short Bs[128 * 32];
    const int tid = threadIdx.x;
    const int flat = blockIdx.x;
    const int xcd = flat & 7, slot = flat >> 3;
    const int m0 = (xcd * 64 + (slot >> 2)) * 128;
    const int e0 = (slot & 3) * 128;
    const int w = tid >> 6, lane = tid & 63, ml = lane & 15, quad = lane >> 4;
    const int wr = w >> 1, wc = w & 1;
    const int srow = tid >> 1, shalf = tid & 1;
    f32x4 acc[4][4] = {};
    for (int k0 = 0; k0 < 512; k0 += 32) {
        const unsigned short* ap = A + (size_t)(m0 + srow) * 512 + k0 + shalf * 16;
        u16x8 ra0 = *(const u16x8*)ap;
        u16x8 ra1 = *(const u16x8*)(ap + 8);
        const unsigned short* bp = B + (size_t)(e0 + srow) * 512 + k0 + shalf * 16;
        u16x8 rb0 = *(const u16x8*)bp;
        u16x8 rb1 = *(const u16x8*)(bp + 8);
        __syncthreads();
        stage_st(As, srow, shalf * 2 + 0, ra0);
        stage_st(As, srow, shalf * 2 + 1, ra1);
        stage_st(Bs, srow, shalf * 2 + 0, rb0);
        stage_st(Bs, srow, shalf * 2 + 1, rb1);
        __syncthreads();
        bf16x8 af[4], bfr[4];
#pragma unroll
        for (int i = 0; i < 4; ++i) {
            af[i]  = frag_ld(As, wr * 4 + i, ml, quad);
            bfr[i] = frag_ld(Bs, wc * 4 + i, ml, quad);
        }
#pragma unroll
        for (int i = 0; i < 4; ++i)
#pragma unroll
            for (int j = 0; j < 4; ++j)
                acc[i][j] = __builtin_amdgcn_mfma_f32_16x16x32_bf16(af[i], bfr[j], acc[i][j], 0, 0, 0);
    }
#pragma unroll
    for (int j = 0; j < 4; ++j) {
        int e = e0 + wc * 64 + j * 16 + ml;
        float bv = bias[e];
#pragma unroll
        for (int i = 0; i < 4; ++i) {
            int mg = m0 + wr * 64 + i * 16 + quad * 4;
#pragma unroll
            for (int r = 0; r < 4; ++r) {
                float v  = acc[i][j][r] + bv;
                float ax = fabsf(v);
                float t  = __expf(-2.0f * ax);
                out[(size_t)(mg + r) * 512 + e] = ax + __logf(1.0f + t) - LN2F_;
            }
        }
    }
}

// ---------------------------------------------------------------------------
// Buffers:
//   d_out: [am 16 MB | Vb 0.5 MB]  (consumed before K3 overwrites d_out)
//   d_ws : [wsT 67 MB (reused for WT after K2) | y 67 MB]
// Order: cvt(V), build_am -> K1 -> K2 -> build_wt -> K3
// ---------------------------------------------------------------------------
extern "C" void kernel_launch(void* const* d_in, const int* in_sizes, int n_in,
                              void* d_out, int out_size, void* d_ws, size_t ws_size,
                              hipStream_t stream) {
    const float* x     = (const float*)d_in[0];
    const float* alpha = (const float*)d_in[1];
    const float* V     = (const float*)d_in[2];
    const float* W     = (const float*)d_in[3];
    const float* b     = (const float*)d_in[4];

    unsigned short* am  = (unsigned short*)d_out;
    unsigned short* Vb  = am + 8388608;
    unsigned short* wsT = (unsigned short*)d_ws;
    unsigned short* y   = wsT + 33554432;
    unsigned short* WT  = wsT;
    float* out = (float*)d_out;

    k_cvt<<<256, 256, 0, stream>>>(V, Vb, 65536);
    k_build_am<<<4096, 256, 0, stream>>>(alpha, am);

    k_gemm1<<<dim3(2048), 256, 0, stream>>>(x, Vb, wsT);
    k_gemm2<<<dim3(1024), 512, 0, stream>>>(wsT, am, y);
    k_build_wt<<<1024, 256, 0, stream>>>(W, WT);
    k_gemm3<<<dim3(2048), 256, 0, stream>>>(y, WT, b, out);
}